// Round 4
// baseline (100.897 us; speedup 1.0000x reference)
//
#include <hip/hip_runtime.h>

// SpatialDisplConv (separable 12x12 displaced gather-conv)
// B=4 C=3 H=W=512 K=11, input1 padded to 522x522.
// R4: LDS-staged gather, ROWS 32->28 (21.6 KB -> 7 blocks/CU),
// launch_bounds(256,6), weight math overlapped with staging.

constexpr int B  = 4;
constexpr int C  = 3;
constexpr int H  = 512;
constexpr int W  = 512;
constexpr int K  = 11;
constexpr int KP = K + 1;              // 12
constexpr int Hp = H + K - 1;          // 522
constexpr int Wp = W + K - 1;          // 522
constexpr int HW = H * W;
constexpr int PLANE1 = Hp * Wp;

constexpr int TW = 32;                 // tile width  (pixels)
constexpr int TH = 8;                  // tile height (pixels)
constexpr int ROWS = 28;               // staged window rows (7 tile span + ~9 dy-floor span + 12)
constexpr int COLS = 64;               // staged window cols
constexpr int CH_STRIDE = ROWS * COLS; // 1792 floats
constexpr int NSROW = C * ROWS;        // 84 staged (c,row) rows

__global__ __launch_bounds__(256, 6) void sdc_kernel(
    const float* __restrict__ in1,   // [B][C][Hp][Wp]
    const float* __restrict__ in2,   // [B][K][H][W]
    const float* __restrict__ in3,   // [B][K][H][W]
    const float* __restrict__ in4,   // [B][2][H][W]
    float* __restrict__ out)         // [B][C][H][W]
{
    __shared__ float lds[C * ROWS * COLS];   // 21504 B
    __shared__ int   red[16];

    const int tid  = threadIdx.x;
    const int lane = tid & 63;
    const int wid  = tid >> 6;
    const int w = blockIdx.x * TW + (tid & (TW - 1));
    const int h = blockIdx.y * TH + (tid >> 5);
    const int b = blockIdx.z;
    const int pix = h * W + w;

    const float dx = in4[(b * 2 + 0) * HW + pix];
    const float dy = in4[(b * 2 + 1) * HW + pix];

    const float py  = (float)h + dy;
    const float px  = (float)w + dx;
    const float fy0 = floorf(py);
    const float fx0 = floorf(px);
    const float wy  = py - fy0;
    const float wx  = px - fx0;
    const int   iy0 = (int)fy0;
    const int   ix0 = (int)fx0;

    // Block-wide min/max of iy0, ix0.
    int mniy = iy0, mxiy = iy0, mnix = ix0, mxix = ix0;
    #pragma unroll
    for (int m = 1; m < 64; m <<= 1) {
        mniy = min(mniy, __shfl_xor(mniy, m, 64));
        mxiy = max(mxiy, __shfl_xor(mxiy, m, 64));
        mnix = min(mnix, __shfl_xor(mnix, m, 64));
        mxix = max(mxix, __shfl_xor(mxix, m, 64));
    }
    if (lane == 0) {
        red[wid * 4 + 0] = mniy;
        red[wid * 4 + 1] = mxiy;
        red[wid * 4 + 2] = mnix;
        red[wid * 4 + 3] = mxix;
    }
    __syncthreads();
    const int row0 = min(min(red[0], red[4]), min(red[8], red[12]));
    const int rmax = max(max(red[1], red[5]), max(red[9], red[13]));
    const int col0 = min(min(red[2], red[6]), min(red[10], red[14]));
    const int cmax = max(max(red[3], red[7]), max(red[11], red[15]));
    const bool fits = (rmax - row0 + KP <= ROWS) && (cmax - col0 + KP <= COLS);

    // Stage first (issue global loads + LDS writes), weights computed after
    // so their VALU overlaps the staging latency before the barrier.
    if (fits) {
        const int   srcc  = min(max(col0 + lane, 0), Wp - 1);
        const float* bb1  = in1 + (size_t)b * C * PLANE1 + srcc;
        #pragma unroll
        for (int s = 0; s < NSROW / 4; ++s) {
            int sr = s * 4 + wid;                 // 0..83
            int c  = sr / ROWS;
            int r  = sr - c * ROWS;
            int srcr = min(max(row0 + r, 0), Hp - 1);
            lds[sr * COLS + lane] = bb1[(c * Hp + srcr) * Wp];
        }
    }

    // Vy[g] = in2[g]*(1-wy) + in2[g-1]*wy (in2[-1]=in2[11]=0); same for Hx.
    // Validity (y for Vy, x for Hx) folded directly into the weights.
    float Vye[KP], Hxe[KP];
    {
        const float* p2 = in2 + b * K * HW + pix;
        const float* p3 = in3 + b * K * HW + pix;
        float v2[K], v3[K];
        #pragma unroll
        for (int k = 0; k < K; ++k) {
            v2[k] = p2[k * HW];
            v3[k] = p3[k * HW];
        }
        const float omwy = 1.f - wy;
        const float omwx = 1.f - wx;
        #pragma unroll
        for (int g = 0; g < KP; ++g) {
            float a2 = (g < K) ? v2[g] : 0.f;
            float b2 = (g > 0) ? v2[g - 1] : 0.f;
            float vy = a2 * omwy + b2 * wy;
            int   iy = iy0 + g;
            Vye[g] = (iy >= 0 && iy < Hp) ? vy : 0.f;
            float a3 = (g < K) ? v3[g] : 0.f;
            float b3 = (g > 0) ? v3[g - 1] : 0.f;
            float hx = a3 * omwx + b3 * wx;
            int   ix = ix0 + g;
            Hxe[g] = (ix >= 0 && ix < Wp) ? hx : 0.f;
        }
    }

    float acc0 = 0.f, acc1 = 0.f, acc2 = 0.f;

    if (fits) {
        __syncthreads();
        // Gather: single base vaddr, all 432 taps via immediate offsets.
        const float* Lp = lds + (iy0 - row0) * COLS + (ix0 - col0);
        #pragma unroll
        for (int gy = 0; gy < KP; ++gy) {
            float s0 = 0.f, s1 = 0.f, s2 = 0.f;
            #pragma unroll
            for (int gx = 0; gx < KP; ++gx) {
                const float hx = Hxe[gx];
                s0 += hx * Lp[gy * COLS + gx];
                s1 += hx * Lp[CH_STRIDE + gy * COLS + gx];
                s2 += hx * Lp[2 * CH_STRIDE + gy * COLS + gx];
            }
            acc0 += Vye[gy] * s0;
            acc1 += Vye[gy] * s1;
            acc2 += Vye[gy] * s2;
        }
    } else {
        // Fallback: global gather (identical semantics, clamped indices).
        const float* base1 = in1 + (size_t)b * C * PLANE1;
        #pragma unroll 1
        for (int gy = 0; gy < KP; ++gy) {
            const int iyc = min(max(iy0 + gy, 0), Hp - 1);
            const float* r = base1 + iyc * Wp;
            float s0 = 0.f, s1 = 0.f, s2 = 0.f;
            #pragma unroll
            for (int gx = 0; gx < KP; ++gx) {
                const int ixc = min(max(ix0 + gx, 0), Wp - 1);
                const float hx = Hxe[gx];
                s0 += hx * r[ixc];
                s1 += hx * r[PLANE1 + ixc];
                s2 += hx * r[2 * PLANE1 + ixc];
            }
            acc0 += Vye[gy] * s0;
            acc1 += Vye[gy] * s1;
            acc2 += Vye[gy] * s2;
        }
    }

    float* po = out + b * C * HW + pix;
    po[0]      = acc0;
    po[HW]     = acc1;
    po[2 * HW] = acc2;
}

extern "C" void kernel_launch(void* const* d_in, const int* in_sizes, int n_in,
                              void* d_out, int out_size, void* d_ws, size_t ws_size,
                              hipStream_t stream) {
    const float* in1 = (const float*)d_in[0];
    const float* in2 = (const float*)d_in[1];
    const float* in3 = (const float*)d_in[2];
    const float* in4 = (const float*)d_in[3];
    float* out = (float*)d_out;

    dim3 grid(W / TW, H / TH, B);       // (16, 64, 4)
    dim3 block(TW * TH);                // 256
    sdc_kernel<<<grid, block, 0, stream>>>(in1, in2, in3, in4, out);
}

// Round 5
// 85.300 us; speedup vs baseline: 1.1829x; 1.1829x over previous
//
#include <hip/hip_runtime.h>

// SpatialDisplConv (separable 12x12 displaced gather-conv)
// B=4 C=3 H=W=512 K=11, input1 padded to 522x522.
// R5: channel-interleaved LDS window [28][64][rgba] (28 KB). One 16B-aligned
// ds_read_b128 per (gy,gx) tap fetches all 3 channels -> 144 LDS reads
// (was 432) and near-conflict-free banking (col jitter moves across 4-bank
// groups). Plain launch_bounds(256) — R4's (256,6) caused scratch spills.

constexpr int B  = 4;
constexpr int C  = 3;
constexpr int H  = 512;
constexpr int W  = 512;
constexpr int K  = 11;
constexpr int KP = K + 1;              // 12
constexpr int Hp = H + K - 1;          // 522
constexpr int Wp = W + K - 1;          // 522
constexpr int HW = H * W;
constexpr int PLANE1 = Hp * Wp;

constexpr int TW = 32;                 // tile width  (pixels)
constexpr int TH = 8;                  // tile height (pixels)
constexpr int ROWS = 28;               // staged window rows
constexpr int COLS = 64;               // staged window cols
constexpr int NSITE = ROWS * COLS;     // 1792 (row,col) sites

__global__ __launch_bounds__(256) void sdc_kernel(
    const float* __restrict__ in1,   // [B][C][Hp][Wp]
    const float* __restrict__ in2,   // [B][K][H][W]
    const float* __restrict__ in3,   // [B][K][H][W]
    const float* __restrict__ in4,   // [B][2][H][W]
    float* __restrict__ out)         // [B][C][H][W]
{
    __shared__ alignas(16) float lds[NSITE * 4];   // 28672 B, [row][col][rgba]
    __shared__ int red[16];

    const int tid  = threadIdx.x;
    const int lane = tid & 63;
    const int wid  = tid >> 6;
    const int w = blockIdx.x * TW + (tid & (TW - 1));
    const int h = blockIdx.y * TH + (tid >> 5);
    const int b = blockIdx.z;
    const int pix = h * W + w;

    const float dx = in4[(b * 2 + 0) * HW + pix];
    const float dy = in4[(b * 2 + 1) * HW + pix];

    const float py  = (float)h + dy;
    const float px  = (float)w + dx;
    const float fy0 = floorf(py);
    const float fx0 = floorf(px);
    const float wy  = py - fy0;
    const float wx  = px - fx0;
    const int   iy0 = (int)fy0;
    const int   ix0 = (int)fx0;

    // Block-wide min/max of iy0, ix0.
    int mniy = iy0, mxiy = iy0, mnix = ix0, mxix = ix0;
    #pragma unroll
    for (int m = 1; m < 64; m <<= 1) {
        mniy = min(mniy, __shfl_xor(mniy, m, 64));
        mxiy = max(mxiy, __shfl_xor(mxiy, m, 64));
        mnix = min(mnix, __shfl_xor(mnix, m, 64));
        mxix = max(mxix, __shfl_xor(mxix, m, 64));
    }
    if (lane == 0) {
        red[wid * 4 + 0] = mniy;
        red[wid * 4 + 1] = mxiy;
        red[wid * 4 + 2] = mnix;
        red[wid * 4 + 3] = mxix;
    }
    __syncthreads();
    const int row0 = min(min(red[0], red[4]), min(red[8], red[12]));
    const int rmax = max(max(red[1], red[5]), max(red[9], red[13]));
    const int col0 = min(min(red[2], red[6]), min(red[10], red[14]));
    const int cmax = max(max(red[3], red[7]), max(red[11], red[15]));
    const bool fits = (rmax - row0 + KP <= ROWS) && (cmax - col0 + KP <= COLS);

    // Cooperative stage: 1792 sites / 256 threads = 7 iters. Each thread
    // loads the 3 channel values for one (row,col) site (coalesced per
    // wave: 64 consecutive cols = one staged row) and writes one float4.
    if (fits) {
        const float* bb1 = in1 + (size_t)b * C * PLANE1;
        #pragma unroll
        for (int it = 0; it < NSITE / 256; ++it) {
            int site = it * 256 + tid;
            int r    = site >> 6;
            int col  = site & 63;
            int srcr = min(max(row0 + r, 0), Hp - 1);
            int srcc = min(max(col0 + col, 0), Wp - 1);
            const float* p = bb1 + srcr * Wp + srcc;
            float c0 = p[0];
            float c1 = p[PLANE1];
            float c2 = p[2 * PLANE1];
            float4* dst = (float4*)&lds[site * 4];
            *dst = make_float4(c0, c1, c2, 0.f);
        }
    }

    // Weights; validity folded in. (Overlaps staging latency pre-barrier.)
    float Vye[KP], Hxe[KP];
    {
        const float* p2 = in2 + b * K * HW + pix;
        const float* p3 = in3 + b * K * HW + pix;
        float v2[K], v3[K];
        #pragma unroll
        for (int k = 0; k < K; ++k) {
            v2[k] = p2[k * HW];
            v3[k] = p3[k * HW];
        }
        const float omwy = 1.f - wy;
        const float omwx = 1.f - wx;
        #pragma unroll
        for (int g = 0; g < KP; ++g) {
            float a2 = (g < K) ? v2[g] : 0.f;
            float b2 = (g > 0) ? v2[g - 1] : 0.f;
            float vy = a2 * omwy + b2 * wy;
            int   iy = iy0 + g;
            Vye[g] = (iy >= 0 && iy < Hp) ? vy : 0.f;
            float a3 = (g < K) ? v3[g] : 0.f;
            float b3 = (g > 0) ? v3[g - 1] : 0.f;
            float hx = a3 * omwx + b3 * wx;
            int   ix = ix0 + g;
            Hxe[g] = (ix >= 0 && ix < Wp) ? hx : 0.f;
        }
    }

    float acc0 = 0.f, acc1 = 0.f, acc2 = 0.f;

    if (fits) {
        __syncthreads();
        // Gather: one b128 per tap (3 channels + pad), single base vaddr,
        // compile-time immediate offsets.
        const float4* Lp = (const float4*)&lds[((iy0 - row0) * COLS + (ix0 - col0)) * 4];
        #pragma unroll
        for (int gy = 0; gy < KP; ++gy) {
            float s0 = 0.f, s1 = 0.f, s2 = 0.f;
            #pragma unroll
            for (int gx = 0; gx < KP; ++gx) {
                float4 f = Lp[gy * COLS + gx];
                const float hx = Hxe[gx];
                s0 += hx * f.x;
                s1 += hx * f.y;
                s2 += hx * f.z;
            }
            acc0 += Vye[gy] * s0;
            acc1 += Vye[gy] * s1;
            acc2 += Vye[gy] * s2;
        }
    } else {
        // Fallback: global gather (identical semantics, clamped indices).
        const float* base1 = in1 + (size_t)b * C * PLANE1;
        #pragma unroll 1
        for (int gy = 0; gy < KP; ++gy) {
            const int iyc = min(max(iy0 + gy, 0), Hp - 1);
            const float* r = base1 + iyc * Wp;
            float s0 = 0.f, s1 = 0.f, s2 = 0.f;
            #pragma unroll
            for (int gx = 0; gx < KP; ++gx) {
                const int ixc = min(max(ix0 + gx, 0), Wp - 1);
                const float hx = Hxe[gx];
                s0 += hx * r[ixc];
                s1 += hx * r[PLANE1 + ixc];
                s2 += hx * r[2 * PLANE1 + ixc];
            }
            acc0 += Vye[gy] * s0;
            acc1 += Vye[gy] * s1;
            acc2 += Vye[gy] * s2;
        }
    }

    float* po = out + b * C * HW + pix;
    po[0]      = acc0;
    po[HW]     = acc1;
    po[2 * HW] = acc2;
}

extern "C" void kernel_launch(void* const* d_in, const int* in_sizes, int n_in,
                              void* d_out, int out_size, void* d_ws, size_t ws_size,
                              hipStream_t stream) {
    const float* in1 = (const float*)d_in[0];
    const float* in2 = (const float*)d_in[1];
    const float* in3 = (const float*)d_in[2];
    const float* in4 = (const float*)d_in[3];
    float* out = (float*)d_out;

    dim3 grid(W / TW, H / TH, B);       // (16, 64, 4)
    dim3 block(TW * TH);                // 256
    sdc_kernel<<<grid, block, 0, stream>>>(in1, in2, in3, in4, out);
}

// Round 6
// 74.168 us; speedup vs baseline: 1.3604x; 1.1501x over previous
//
#include <hip/hip_runtime.h>
#include <stdint.h>

// SpatialDisplConv — R6: f16 LDS window + v_dot2_f32_f16 gather.
// Layout: per channel [32 rows][68 f16] with 136B row stride (34 dwords ->
// bank drift 2/row decorrelates row-jitter from column-jitter conflicts).
// Gather per (gy,ch): 4x ds_read_b64 (16 cols) + 8x v_dot2 with a 16-wide
// parity-shifted f16x2 weight vector. Halves LDS bytes vs R3.

typedef _Float16 half_t;
typedef half_t half2_t __attribute__((ext_vector_type(2)));

constexpr int B  = 4;
constexpr int C  = 3;
constexpr int H  = 512;
constexpr int W  = 512;
constexpr int K  = 11;
constexpr int KP = K + 1;              // 12
constexpr int Hp = H + K - 1;          // 522
constexpr int Wp = W + K - 1;          // 522
constexpr int HW = H * W;
constexpr int PLANE1 = Hp * Wp;

constexpr int TW   = 32;               // tile width  (pixels)
constexpr int TH   = 8;                // tile height (pixels)
constexpr int ROWS = 32;               // staged window rows
constexpr int COLS = 64;               // staged usable cols
constexpr int ROWB = 136;              // bytes per LDS row (68 f16: 64 + 4 pad)
constexpr int CHB  = ROWS * ROWB;      // 4352 B per channel plane

__global__ __launch_bounds__(256) void sdc_kernel(
    const float* __restrict__ in1,   // [B][C][Hp][Wp]
    const float* __restrict__ in2,   // [B][K][H][W]
    const float* __restrict__ in3,   // [B][K][H][W]
    const float* __restrict__ in4,   // [B][2][H][W]
    float* __restrict__ out)         // [B][C][H][W]
{
    __shared__ char lds[C * CHB];    // 13056 B
    __shared__ int  red[16];

    const int tid  = threadIdx.x;
    const int lane = tid & 63;
    const int wid  = tid >> 6;
    const int w = blockIdx.x * TW + (tid & (TW - 1));
    const int h = blockIdx.y * TH + (tid >> 5);
    const int b = blockIdx.z;
    const int pix = h * W + w;

    const float dx = in4[(b * 2 + 0) * HW + pix];
    const float dy = in4[(b * 2 + 1) * HW + pix];

    const float py  = (float)h + dy;
    const float px  = (float)w + dx;
    const float fy0 = floorf(py);
    const float fx0 = floorf(px);
    const float wy  = py - fy0;
    const float wx  = px - fx0;
    const int   iy0 = (int)fy0;
    const int   ix0 = (int)fx0;

    // Block-wide min/max of iy0, ix0.
    int mniy = iy0, mxiy = iy0, mnix = ix0, mxix = ix0;
    #pragma unroll
    for (int m = 1; m < 64; m <<= 1) {
        mniy = min(mniy, __shfl_xor(mniy, m, 64));
        mxiy = max(mxiy, __shfl_xor(mxiy, m, 64));
        mnix = min(mnix, __shfl_xor(mnix, m, 64));
        mxix = max(mxix, __shfl_xor(mxix, m, 64));
    }
    if (lane == 0) {
        red[wid * 4 + 0] = mniy;
        red[wid * 4 + 1] = mxiy;
        red[wid * 4 + 2] = mnix;
        red[wid * 4 + 3] = mxix;
    }
    __syncthreads();
    const int row0 = min(min(red[0], red[4]), min(red[8], red[12]));
    const int rmax = max(max(red[1], red[5]), max(red[9], red[13]));
    const int col0 = min(min(red[2], red[6]), min(red[10], red[14]));
    const int cmax = max(max(red[3], red[7]), max(red[11], red[15]));
    const bool fits = (rmax - row0 + KP <= ROWS) && (cmax - col0 + KP <= COLS);

    // ---- Cooperative stage: f32 -> f16 pairs -> LDS b32 writes ----
    // Main: 96 (c,row) x 32 col-pairs = 3072 sites / 256 = 12 iters.
    // Pad:  96 (c,row) x 2 pad pairs (cols 64..67, clamped real data so no
    //       NaN can ever be read even under zero weights).
    if (fits) {
        const float* bb1 = in1 + (size_t)b * C * PLANE1;
        #pragma unroll
        for (int it = 0; it < 12; ++it) {
            int idx = it * 256 + tid;
            int cp  = idx & 31;            // col pair 0..31
            int cr  = idx >> 5;            // 0..95
            int c   = cr >> 5;             // ROWS==32
            int r   = cr & 31;
            int srcr = min(max(row0 + r, 0), Hp - 1);
            int gc0  = col0 + 2 * cp;
            int s0c  = min(max(gc0, 0), Wp - 1);
            int s1c  = min(max(gc0 + 1, 0), Wp - 1);
            const float* p = bb1 + (size_t)c * PLANE1 + (size_t)srcr * Wp;
            half2_t hv;
            hv.x = (half_t)p[s0c];
            hv.y = (half_t)p[s1c];
            *(uint32_t*)(lds + c * CHB + r * ROWB + cp * 4) =
                __builtin_bit_cast(uint32_t, hv);
        }
        if (tid < 192) {
            int cr = tid >> 1;             // 0..95
            int c  = cr >> 5;
            int r  = cr & 31;
            int cp = 32 + (tid & 1);       // pad pairs 32,33 (cols 64..67)
            int srcr = min(max(row0 + r, 0), Hp - 1);
            int gc0  = col0 + 2 * cp;
            int s0c  = min(max(gc0, 0), Wp - 1);
            int s1c  = min(max(gc0 + 1, 0), Wp - 1);
            const float* p = bb1 + (size_t)c * PLANE1 + (size_t)srcr * Wp;
            half2_t hv;
            hv.x = (half_t)p[s0c];
            hv.y = (half_t)p[s1c];
            *(uint32_t*)(lds + c * CHB + r * ROWB + cp * 4) =
                __builtin_bit_cast(uint32_t, hv);
        }
    }

    // ---- Weights (overlap staging latency before the barrier) ----
    float Vye[KP], Hxe[KP];
    {
        const float* p2 = in2 + b * K * HW + pix;
        const float* p3 = in3 + b * K * HW + pix;
        float v2[K], v3[K];
        #pragma unroll
        for (int k = 0; k < K; ++k) {
            v2[k] = p2[k * HW];
            v3[k] = p3[k * HW];
        }
        const float omwy = 1.f - wy;
        const float omwx = 1.f - wx;
        #pragma unroll
        for (int g = 0; g < KP; ++g) {
            float a2 = (g < K) ? v2[g] : 0.f;
            float b2 = (g > 0) ? v2[g - 1] : 0.f;
            float vy = a2 * omwy + b2 * wy;
            int   iy = iy0 + g;
            Vye[g] = (iy >= 0 && iy < Hp) ? vy : 0.f;
            float a3 = (g < K) ? v3[g] : 0.f;
            float b3 = (g > 0) ? v3[g - 1] : 0.f;
            float hx = a3 * omwx + b3 * wx;
            int   ix = ix0 + g;
            Hxe[g] = (ix >= 0 && ix < Wp) ? hx : 0.f;
        }
    }

    float acc0 = 0.f, acc1 = 0.f, acc2 = 0.f;

    if (fits) {
        // 16-wide parity-shifted f16x2 weight vector: window starts at
        // s = ix0-col0; a4 = s&~3 (8B-aligned col), e2 = s&3 in 0..3.
        // Wf[j] = Hxe[j-e2] for j-e2 in [0,12), else 0. All Hxe indices
        // compile-time (select chain), no scratch.
        const int s  = ix0 - col0;
        const int a4 = s & ~3;
        const int e2 = s & 3;
        half2_t W2[8];
        {
            const bool is1 = (e2 == 1), is2 = (e2 == 2), is3 = (e2 == 3);
            float Wf[16];
            #pragma unroll
            for (int j = 0; j < 16; ++j) {
                float v0 = (j < 12) ? Hxe[j] : 0.f;
                float v1 = (j >= 1 && j <= 12) ? Hxe[j - 1] : 0.f;
                float v2_ = (j >= 2 && j <= 13) ? Hxe[j - 2] : 0.f;
                float v3_ = (j >= 3 && j <= 14) ? Hxe[j - 3] : 0.f;
                Wf[j] = is3 ? v3_ : (is2 ? v2_ : (is1 ? v1 : v0));
            }
            #pragma unroll
            for (int p = 0; p < 8; ++p) {
                half2_t hw;
                hw.x = (half_t)Wf[2 * p];
                hw.y = (half_t)Wf[2 * p + 1];
                W2[p] = hw;
            }
        }

        __syncthreads();

        const int ry = iy0 - row0;
        const char* lb = lds + ry * ROWB + (a4 << 1);  // 8B-aligned base
        #pragma unroll
        for (int gy = 0; gy < KP; ++gy) {
            float sc[3];
            #pragma unroll
            for (int c = 0; c < 3; ++c) {
                float s_ = 0.f;
                #pragma unroll
                for (int blk = 0; blk < 4; ++blk) {
                    uint2 q = *(const uint2*)(lb + c * CHB + gy * ROWB + 8 * blk);
                    s_ = __builtin_amdgcn_fdot2(
                            __builtin_bit_cast(half2_t, q.x), W2[2 * blk], s_, false);
                    s_ = __builtin_amdgcn_fdot2(
                            __builtin_bit_cast(half2_t, q.y), W2[2 * blk + 1], s_, false);
                }
                sc[c] = s_;
            }
            acc0 += Vye[gy] * sc[0];
            acc1 += Vye[gy] * sc[1];
            acc2 += Vye[gy] * sc[2];
        }
    } else {
        // Fallback: global f32 gather (identical semantics, clamped indices).
        const float* base1 = in1 + (size_t)b * C * PLANE1;
        #pragma unroll 1
        for (int gy = 0; gy < KP; ++gy) {
            const int iyc = min(max(iy0 + gy, 0), Hp - 1);
            const float* r = base1 + iyc * Wp;
            float s0 = 0.f, s1 = 0.f, s2 = 0.f;
            #pragma unroll
            for (int gx = 0; gx < KP; ++gx) {
                const int ixc = min(max(ix0 + gx, 0), Wp - 1);
                const float hx = Hxe[gx];
                s0 += hx * r[ixc];
                s1 += hx * r[PLANE1 + ixc];
                s2 += hx * r[2 * PLANE1 + ixc];
            }
            acc0 += Vye[gy] * s0;
            acc1 += Vye[gy] * s1;
            acc2 += Vye[gy] * s2;
        }
    }

    float* po = out + b * C * HW + pix;
    po[0]      = acc0;
    po[HW]     = acc1;
    po[2 * HW] = acc2;
}

extern "C" void kernel_launch(void* const* d_in, const int* in_sizes, int n_in,
                              void* d_out, int out_size, void* d_ws, size_t ws_size,
                              hipStream_t stream) {
    const float* in1 = (const float*)d_in[0];
    const float* in2 = (const float*)d_in[1];
    const float* in3 = (const float*)d_in[2];
    const float* in4 = (const float*)d_in[3];
    float* out = (float*)d_out;

    dim3 grid(W / TW, H / TH, B);       // (16, 64, 4)
    dim3 block(TW * TH);                // 256
    sdc_kernel<<<grid, block, 0, stream>>>(in1, in2, in3, in4, out);
}

// Round 7
// 56.252 us; speedup vs baseline: 1.7937x; 1.3185x over previous
//
#include <hip/hip_runtime.h>
#include <stdint.h>

// SpatialDisplConv — R7: uniform-row LDS gather.
// Window in LDS as f16 [c][32 rows][68] (136B stride, 13KB). Gather loops
// over STAGED row r (compile-time): ds address = uniform row/ch + per-lane
// column only -> bank conflicts structurally eliminated. Vertical weight for
// static r comes from a 28-slot barrel-shifted frame F[r] = Vye[r-(iy0-row0)]
// (5 cndmask stages, all static indices). Wave-uniform skip of inactive rows.

typedef _Float16 half_t;
typedef half_t half2_t __attribute__((ext_vector_type(2)));

constexpr int B  = 4;
constexpr int C  = 3;
constexpr int H  = 512;
constexpr int W  = 512;
constexpr int K  = 11;
constexpr int KP = K + 1;              // 12
constexpr int Hp = H + K - 1;          // 522
constexpr int Wp = W + K - 1;          // 522
constexpr int HW = H * W;
constexpr int PLANE1 = Hp * Wp;

constexpr int TW   = 32;               // tile width  (pixels)
constexpr int TH   = 8;                // tile height (pixels)
constexpr int ROWS = 32;               // staged window rows
constexpr int COLS = 64;               // staged usable cols
constexpr int ROWB = 136;              // bytes per LDS row (68 f16)
constexpr int CHB  = ROWS * ROWB;      // 4352 B per channel plane

__global__ __launch_bounds__(256) void sdc_kernel(
    const float* __restrict__ in1,   // [B][C][Hp][Wp]
    const float* __restrict__ in2,   // [B][K][H][W]
    const float* __restrict__ in3,   // [B][K][H][W]
    const float* __restrict__ in4,   // [B][2][H][W]
    float* __restrict__ out)         // [B][C][H][W]
{
    __shared__ char lds[C * CHB];    // 13056 B
    __shared__ int  red[16];

    const int tid  = threadIdx.x;
    const int lane = tid & 63;
    const int wid  = tid >> 6;
    const int w = blockIdx.x * TW + (tid & (TW - 1));
    const int h = blockIdx.y * TH + (tid >> 5);
    const int b = blockIdx.z;
    const int pix = h * W + w;

    const float dx = in4[(b * 2 + 0) * HW + pix];
    const float dy = in4[(b * 2 + 1) * HW + pix];

    const float py  = (float)h + dy;
    const float px  = (float)w + dx;
    const float fy0 = floorf(py);
    const float fx0 = floorf(px);
    const float wy  = py - fy0;
    const float wx  = px - fx0;
    const int   iy0 = (int)fy0;
    const int   ix0 = (int)fx0;

    // Wave + block min/max of iy0, ix0.
    int mniy = iy0, mxiy = iy0, mnix = ix0, mxix = ix0;
    #pragma unroll
    for (int m = 1; m < 64; m <<= 1) {
        mniy = min(mniy, __shfl_xor(mniy, m, 64));
        mxiy = max(mxiy, __shfl_xor(mxiy, m, 64));
        mnix = min(mnix, __shfl_xor(mnix, m, 64));
        mxix = max(mxix, __shfl_xor(mxix, m, 64));
    }
    const int wv_mniy = mniy, wv_mxiy = mxiy;   // wave-level (uniform)
    if (lane == 0) {
        red[wid * 4 + 0] = mniy;
        red[wid * 4 + 1] = mxiy;
        red[wid * 4 + 2] = mnix;
        red[wid * 4 + 3] = mxix;
    }
    __syncthreads();
    const int row0 = min(min(red[0], red[4]), min(red[8], red[12]));
    const int rmax = max(max(red[1], red[5]), max(red[9], red[13]));
    const int col0 = min(min(red[2], red[6]), min(red[10], red[14]));
    const int cmax = max(max(red[3], red[7]), max(red[11], red[15]));
    const bool fits = (rmax - row0 + KP <= ROWS) && (cmax - col0 + KP <= COLS);

    // ---- Cooperative stage: f32 -> f16 pairs -> LDS b32 writes ----
    if (fits) {
        const float* bb1 = in1 + (size_t)b * C * PLANE1;
        #pragma unroll
        for (int it = 0; it < 12; ++it) {
            int idx = it * 256 + tid;
            int cp  = idx & 31;            // col pair 0..31
            int cr  = idx >> 5;            // 0..95
            int c   = cr >> 5;             // ROWS==32
            int r   = cr & 31;
            int srcr = min(max(row0 + r, 0), Hp - 1);
            int gc0  = col0 + 2 * cp;
            int s0c  = min(max(gc0, 0), Wp - 1);
            int s1c  = min(max(gc0 + 1, 0), Wp - 1);
            const float* p = bb1 + (size_t)c * PLANE1 + (size_t)srcr * Wp;
            half2_t hv;
            hv.x = (half_t)p[s0c];
            hv.y = (half_t)p[s1c];
            *(uint32_t*)(lds + c * CHB + r * ROWB + cp * 4) =
                __builtin_bit_cast(uint32_t, hv);
        }
        if (tid < 192) {
            int cr = tid >> 1;             // 0..95
            int c  = cr >> 5;
            int r  = cr & 31;
            int cp = 32 + (tid & 1);       // pad pairs (cols 64..67)
            int srcr = min(max(row0 + r, 0), Hp - 1);
            int gc0  = col0 + 2 * cp;
            int s0c  = min(max(gc0, 0), Wp - 1);
            int s1c  = min(max(gc0 + 1, 0), Wp - 1);
            const float* p = bb1 + (size_t)c * PLANE1 + (size_t)srcr * Wp;
            half2_t hv;
            hv.x = (half_t)p[s0c];
            hv.y = (half_t)p[s1c];
            *(uint32_t*)(lds + c * CHB + r * ROWB + cp * 4) =
                __builtin_bit_cast(uint32_t, hv);
        }
    }

    // ---- Weights (overlap staging latency before the barrier) ----
    float Vye[KP], Hxe[KP];
    {
        const float* p2 = in2 + b * K * HW + pix;
        const float* p3 = in3 + b * K * HW + pix;
        float v2[K], v3[K];
        #pragma unroll
        for (int k = 0; k < K; ++k) {
            v2[k] = p2[k * HW];
            v3[k] = p3[k * HW];
        }
        const float omwy = 1.f - wy;
        const float omwx = 1.f - wx;
        #pragma unroll
        for (int g = 0; g < KP; ++g) {
            float a2 = (g < K) ? v2[g] : 0.f;
            float b2 = (g > 0) ? v2[g - 1] : 0.f;
            float vy = a2 * omwy + b2 * wy;
            int   iy = iy0 + g;
            Vye[g] = (iy >= 0 && iy < Hp) ? vy : 0.f;
            float a3 = (g < K) ? v3[g] : 0.f;
            float b3 = (g > 0) ? v3[g - 1] : 0.f;
            float hx = a3 * omwx + b3 * wx;
            int   ix = ix0 + g;
            Hxe[g] = (ix >= 0 && ix < Wp) ? hx : 0.f;
        }
    }

    float acc0 = 0.f, acc1 = 0.f, acc2 = 0.f;

    if (fits) {
        // 16-wide parity-shifted f16x2 horizontal weight vector (as R6).
        const int s  = ix0 - col0;
        const int a4 = s & ~3;
        const int e2 = s & 3;
        half2_t W2[8];
        {
            const bool is1 = (e2 == 1), is2 = (e2 == 2), is3 = (e2 == 3);
            float Wf[16];
            #pragma unroll
            for (int j = 0; j < 16; ++j) {
                float v0  = (j < 12) ? Hxe[j] : 0.f;
                float v1  = (j >= 1 && j <= 12) ? Hxe[j - 1] : 0.f;
                float v2_ = (j >= 2 && j <= 13) ? Hxe[j - 2] : 0.f;
                float v3_ = (j >= 3 && j <= 14) ? Hxe[j - 3] : 0.f;
                Wf[j] = is3 ? v3_ : (is2 ? v2_ : (is1 ? v1 : v0));
            }
            #pragma unroll
            for (int p = 0; p < 8; ++p) {
                half2_t hw;
                hw.x = (half_t)Wf[2 * p];
                hw.y = (half_t)Wf[2 * p + 1];
                W2[p] = hw;
            }
        }

        // Vertical weight frame: F[r] = Vye[r - sh], sh = iy0-row0 in [0,16].
        // Barrel shift with static indices only.
        float F[ROWS];
        #pragma unroll
        for (int i = 0; i < ROWS; ++i) F[i] = (i < KP) ? Vye[i] : 0.f;
        const int sh = iy0 - row0;
        #pragma unroll
        for (int st = 16; st >= 1; st >>= 1) {
            const bool c = (sh & st) != 0;
            #pragma unroll
            for (int i = ROWS - 1; i >= 0; --i) {
                float shifted = (i - st >= 0) ? F[i - st] : 0.f;
                F[i] = c ? shifted : F[i];
            }
        }

        // Wave-uniform active-row range.
        const int rlo = __builtin_amdgcn_readfirstlane(max(0, wv_mniy - row0));
        const int rhi = __builtin_amdgcn_readfirstlane(min(ROWS, wv_mxiy - row0 + KP));

        __syncthreads();

        const char* lb = lds + (a4 << 1);   // per-lane column base (8B aligned)
        #pragma unroll
        for (int r = 0; r < ROWS; ++r) {
            if (r >= rlo && r < rhi) {
                float sc0 = 0.f, sc1 = 0.f, sc2 = 0.f;
                #pragma unroll
                for (int blk = 0; blk < 4; ++blk) {
                    uint2 q0 = *(const uint2*)(lb + 0 * CHB + r * ROWB + 8 * blk);
                    uint2 q1 = *(const uint2*)(lb + 1 * CHB + r * ROWB + 8 * blk);
                    uint2 q2 = *(const uint2*)(lb + 2 * CHB + r * ROWB + 8 * blk);
                    sc0 = __builtin_amdgcn_fdot2(__builtin_bit_cast(half2_t, q0.x), W2[2 * blk],     sc0, false);
                    sc0 = __builtin_amdgcn_fdot2(__builtin_bit_cast(half2_t, q0.y), W2[2 * blk + 1], sc0, false);
                    sc1 = __builtin_amdgcn_fdot2(__builtin_bit_cast(half2_t, q1.x), W2[2 * blk],     sc1, false);
                    sc1 = __builtin_amdgcn_fdot2(__builtin_bit_cast(half2_t, q1.y), W2[2 * blk + 1], sc1, false);
                    sc2 = __builtin_amdgcn_fdot2(__builtin_bit_cast(half2_t, q2.x), W2[2 * blk],     sc2, false);
                    sc2 = __builtin_amdgcn_fdot2(__builtin_bit_cast(half2_t, q2.y), W2[2 * blk + 1], sc2, false);
                }
                acc0 += F[r] * sc0;
                acc1 += F[r] * sc1;
                acc2 += F[r] * sc2;
            }
        }
    } else {
        // Fallback: global f32 gather (identical semantics, clamped indices).
        const float* base1 = in1 + (size_t)b * C * PLANE1;
        #pragma unroll 1
        for (int gy = 0; gy < KP; ++gy) {
            const int iyc = min(max(iy0 + gy, 0), Hp - 1);
            const float* r = base1 + iyc * Wp;
            float s0 = 0.f, s1 = 0.f, s2 = 0.f;
            #pragma unroll
            for (int gx = 0; gx < KP; ++gx) {
                const int ixc = min(max(ix0 + gx, 0), Wp - 1);
                const float hx = Hxe[gx];
                s0 += hx * r[ixc];
                s1 += hx * r[PLANE1 + ixc];
                s2 += hx * r[2 * PLANE1 + ixc];
            }
            acc0 += Vye[gy] * s0;
            acc1 += Vye[gy] * s1;
            acc2 += Vye[gy] * s2;
        }
    }

    float* po = out + b * C * HW + pix;
    po[0]      = acc0;
    po[HW]     = acc1;
    po[2 * HW] = acc2;
}

extern "C" void kernel_launch(void* const* d_in, const int* in_sizes, int n_in,
                              void* d_out, int out_size, void* d_ws, size_t ws_size,
                              hipStream_t stream) {
    const float* in1 = (const float*)d_in[0];
    const float* in2 = (const float*)d_in[1];
    const float* in3 = (const float*)d_in[2];
    const float* in4 = (const float*)d_in[3];
    float* out = (float*)d_out;

    dim3 grid(W / TW, H / TH, B);       // (16, 64, 4)
    dim3 block(TW * TH);                // 256
    sdc_kernel<<<grid, block, 0, stream>>>(in1, in2, in3, in4, out);
}